// Round 7
// baseline (417.581 us; speedup 1.0000x reference)
//
#include <hip/hip_runtime.h>
#include <math.h>

// Problem constants (fixed by the reference)
#define MM 12       // M
#define KK 2        // K
#define DD 512      // D
#define CIN 4096    // C_IN
#define NCLS 8
#define NV 16       // N (videos) == LSTM step count
#define TT 32       // T
// Only LSTM batch row t=31 is ever consumed (rows independent; out uses hs[:, -1, :]).

typedef unsigned long long u64;
typedef __attribute__((ext_vector_type(8))) __bf16 bf16x8;
typedef __attribute__((ext_vector_type(4))) float f32x4;

// ws float offsets
#define PART_F   0            // 4*192*1024 floats
#define POOLED_F 786432       // 16*512
#define SLOTC_F  795136       // clean slots: 4 reps * 16*512 u64 = 65536 floats
#define SLOTC_END_BYTES ((size_t)(795136 + 65536) * 4)
#define PART_KS_STRIDE (192 * 1024)

#define MFMA_BF16(A, B, C) __builtin_amdgcn_mfma_f32_16x16x32_bf16((A), (B), (C), 0, 0, 0)

// ---------------------------------------------------------------------------
// Kernel 1: GEMM part[ks][j][o] = w_a[o,:chunk] . base_sel[j,:chunk]
// bf16x3 MFMA (hi/lo split), tile 16o x 192j per WG, KS=4, 32cc stages.
// 256 WGs (1/CU). Numerics proven in R5/R6 (absmax 1.9e-6).
// ---------------------------------------------------------------------------
__global__ __launch_bounds__(256, 1) void k_gemm(const float* __restrict__ w_a,
                                                 const float* __restrict__ base_out,
                                                 float* __restrict__ part) {
  const int wg = blockIdx.x;   // 0..255
  const int tid = threadIdx.x;

  __shared__ __align__(16) unsigned short Ah[16 * 40], Al[16 * 40];
  __shared__ __align__(16) unsigned short Bh[192 * 40], Bl[192 * 40];

  const int ks = wg >> 6, ot = wg & 63;
  const int cc0 = ks * 1024;
  const int wave = tid >> 6, lane = tid & 63;
  const int jf0 = wave * 3;

  const int sq = tid & 7;
  const int sr = tid >> 3;
  unsigned boff[6];
#pragma unroll
  for (int rep = 0; rep < 6; ++rep) {
    const int j = sr + 32 * rep;
    const int n = j / 12, m = j - n * 12;
    boff[rep] = (unsigned)(((n * TT + 31) * MM + m) * CIN + cc0 + sq * 4);
  }
  const bool aact = tid < 128;
  unsigned aoff = aact ? (unsigned)((ot * 16 + (tid >> 3)) * CIN + cc0 + sq * 4) : 0u;

  f32x4 acc0 = {0.f, 0.f, 0.f, 0.f}, acc1 = acc0, acc2 = acc0;

  float4 pa, pb[6];
  if (aact) pa = *(const float4*)&w_a[aoff];
#pragma unroll
  for (int rep = 0; rep < 6; ++rep) pb[rep] = *(const float4*)&base_out[boff[rep]];

  for (int st = 0; st < 32; ++st) {
    __syncthreads();
    if (aact) {
      const int idx = (tid >> 3) * 40 + sq * 4;
      unsigned ux = __float_as_uint(pa.x), uy = __float_as_uint(pa.y);
      unsigned uz = __float_as_uint(pa.z), uw = __float_as_uint(pa.w);
      *(uint2*)&Ah[idx] = make_uint2((ux >> 16) | (uy & 0xFFFF0000u),
                                     (uz >> 16) | (uw & 0xFFFF0000u));
      unsigned lx = __float_as_uint(pa.x - __uint_as_float(ux & 0xFFFF0000u));
      unsigned ly = __float_as_uint(pa.y - __uint_as_float(uy & 0xFFFF0000u));
      unsigned lz = __float_as_uint(pa.z - __uint_as_float(uz & 0xFFFF0000u));
      unsigned lw = __float_as_uint(pa.w - __uint_as_float(uw & 0xFFFF0000u));
      *(uint2*)&Al[idx] = make_uint2((lx >> 16) | (ly & 0xFFFF0000u),
                                     (lz >> 16) | (lw & 0xFFFF0000u));
    }
#pragma unroll
    for (int rep = 0; rep < 6; ++rep) {
      const int idx = (sr + 32 * rep) * 40 + sq * 4;
      unsigned ux = __float_as_uint(pb[rep].x), uy = __float_as_uint(pb[rep].y);
      unsigned uz = __float_as_uint(pb[rep].z), uw = __float_as_uint(pb[rep].w);
      *(uint2*)&Bh[idx] = make_uint2((ux >> 16) | (uy & 0xFFFF0000u),
                                     (uz >> 16) | (uw & 0xFFFF0000u));
      unsigned lx = __float_as_uint(pb[rep].x - __uint_as_float(ux & 0xFFFF0000u));
      unsigned ly = __float_as_uint(pb[rep].y - __uint_as_float(uy & 0xFFFF0000u));
      unsigned lz = __float_as_uint(pb[rep].z - __uint_as_float(uz & 0xFFFF0000u));
      unsigned lw = __float_as_uint(pb[rep].w - __uint_as_float(uw & 0xFFFF0000u));
      *(uint2*)&Bl[idx] = make_uint2((lx >> 16) | (ly & 0xFFFF0000u),
                                     (lz >> 16) | (lw & 0xFFFF0000u));
    }
    __syncthreads();
    if (st < 31) {
      aoff += 32;
      if (aact) pa = *(const float4*)&w_a[aoff];
#pragma unroll
      for (int rep = 0; rep < 6; ++rep) {
        boff[rep] += 32;
        pb[rep] = *(const float4*)&base_out[boff[rep]];
      }
    }
    const int koff = (lane >> 4) * 8;
    const int fra = (lane & 15) * 40 + koff;
    bf16x8 oh = *(const bf16x8*)&Ah[fra];
    bf16x8 ol = *(const bf16x8*)&Al[fra];
    {
      const int r0 = ((jf0 + 0) * 16 + (lane & 15)) * 40 + koff;
      bf16x8 jh = *(const bf16x8*)&Bh[r0], jl = *(const bf16x8*)&Bl[r0];
      acc0 = MFMA_BF16(jh, oh, acc0);
      acc0 = MFMA_BF16(jh, ol, acc0);
      acc0 = MFMA_BF16(jl, oh, acc0);
    }
    {
      const int r1 = ((jf0 + 1) * 16 + (lane & 15)) * 40 + koff;
      bf16x8 jh = *(const bf16x8*)&Bh[r1], jl = *(const bf16x8*)&Bl[r1];
      acc1 = MFMA_BF16(jh, oh, acc1);
      acc1 = MFMA_BF16(jh, ol, acc1);
      acc1 = MFMA_BF16(jl, oh, acc1);
    }
    {
      const int r2 = ((jf0 + 2) * 16 + (lane & 15)) * 40 + koff;
      bf16x8 jh = *(const bf16x8*)&Bh[r2], jl = *(const bf16x8*)&Bl[r2];
      acc2 = MFMA_BF16(jh, oh, acc2);
      acc2 = MFMA_BF16(jh, ol, acc2);
      acc2 = MFMA_BF16(jl, oh, acc2);
    }
  }
  // C/D layout: col(o) = lane&15, row(j) = (lane>>4)*4 + reg   [m89-verified]
  const int o = ot * 16 + (lane & 15);
  const int jr = (lane >> 4) * 4;
#pragma unroll
  for (int r = 0; r < 4; ++r) {
    part[((size_t)ks * 192 + (jf0 + 0) * 16 + jr + r) * 1024 + o] = acc0[r];
    part[((size_t)ks * 192 + (jf0 + 1) * 16 + jr + r) * 1024 + o] = acc1[r];
    part[((size_t)ks * 192 + (jf0 + 2) * 16 + jr + r) * 1024 + o] = acc2[r];
  }
}

// ---------------------------------------------------------------------------
// Kernel 2: pool — WG (n = wg>>4, c-block = (wg&15)*32); 256 WGs.
// ---------------------------------------------------------------------------
__global__ __launch_bounds__(256) void k_pool(const float* __restrict__ part,
                                              const float* __restrict__ dist,
                                              float* __restrict__ pooled) {
  const int wg = blockIdx.x;
  const int tid = threadIdx.x;
  __shared__ float Asum_s[KK * MM * MM];
  const int n = wg >> 4, cb = (wg & 15) * 32;
  const unsigned dbase = (unsigned)((n * TT + 31) * (3 * KK * MM * MM));
  for (int f = tid; f < KK * MM * MM; f += 256)
    Asum_s[f] = dist[dbase + f] + dist[dbase + KK * MM * MM + f]
              + dist[dbase + 2 * KK * MM * MM + f];
  __syncthreads();
  if (tid < 32) {
    const int c = cb + tid;
    float nd[KK][MM];
#pragma unroll
    for (int k = 0; k < KK; ++k)
#pragma unroll
      for (int v = 0; v < MM; ++v) {
        const size_t off = (size_t)(n * MM + v) * 1024 + k * DD + c;
        nd[k][v] = part[off] + part[off + PART_KS_STRIDE]
                 + part[off + 2 * PART_KS_STRIDE] + part[off + 3 * PART_KS_STRIDE];
      }
    float accm = 0.f;
#pragma unroll
    for (int w = 0; w < MM; ++w) {
      float sw = 0.f;
#pragma unroll
      for (int k = 0; k < KK; ++k)
#pragma unroll
        for (int v = 0; v < MM; ++v) sw += nd[k][v] * Asum_s[(k * MM + v) * MM + w];
      accm += fmaxf(sw, 0.f);
    }
    pooled[n * DD + c] = accm * (1.f / 12.f);
  }
}

// ---------------------------------------------------------------------------
// Kernel 3: LSTM. 32 WGs x 512 threads. WG wg owns dims [16wg,16wg+16).
// w_hh slice lives in REGISTERS (thread (r=tid>>3, l=tid&7): row r=gate*16+dl,
// 64 floats). gx computed in preamble (w_ih rows in LDS). Per step: one
// tagged-u64 poll per thread (4 replicas spread read load), register dot with
// LDS-broadcast h, shfl-reduce over 8 lanes, 2 barriers.
// ---------------------------------------------------------------------------
__global__ __launch_bounds__(512, 1) void k_lstm(const float* __restrict__ w_hh,
                                                 const float* __restrict__ w_ih,
                                                 const float* __restrict__ b_ih,
                                                 const float* __restrict__ b_hh,
                                                 const float* __restrict__ pooled,
                                                 u64* __restrict__ slots) {
  const int wg = blockIdx.x;   // 0..31
  const int tid = threadIdx.x; // 0..511
  const int r = tid >> 3;      // row 0..63  (= gate*16 + dl)
  const int l = tid & 7;       // 64-elem slice
  const int grow = (r >> 4) * DD + wg * 16 + (r & 15);

  __shared__ __align__(16) float wih_s[64][516];
  __shared__ __align__(16) float h_s[DD];
  __shared__ float dot_s[64];
  __shared__ float gx_s[16][64];   // [n][r]

  // w_hh slice -> registers
  float4 wr[16];
#pragma unroll
  for (int q = 0; q < 16; ++q)
    wr[q] = *(const float4*)&w_hh[(size_t)grow * DD + l * 64 + q * 4];

  // stage w_ih rows (coalesced, one row per iteration)
  for (int it = 0; it < 64; ++it) {
    const int rg = (it >> 4) * DD + wg * 16 + (it & 15);
    wih_s[it][tid] = w_ih[(size_t)rg * DD + tid];
  }
  __syncthreads();

  // gx preamble: 1024 dots (64 rows x 16 n), 2 per thread
  for (int idx = tid; idx < 1024; idx += 512) {
    const int rr = idx >> 4, n = idx & 15;
    const float4* wv = (const float4*)&wih_s[rr][0];
    const float4* pv = (const float4*)&pooled[n * DD];
    float a = 0.f;
#pragma unroll 8
    for (int q = 0; q < DD / 4; ++q) {
      float4 x = wv[q], y = pv[q];
      a += x.x * y.x + x.y * y.y + x.z * y.z + x.w * y.w;
    }
    const int rg = (rr >> 4) * DD + wg * 16 + (rr & 15);
    gx_s[n][rr] = a + b_ih[rg] + b_hh[rg];
  }
  __syncthreads();

  float c_reg = 0.f;
  const int rep = wg & 3;

  for (int s = 0; s < NV; ++s) {
    // ---- gather h_{s-1}: ONE tagged slot per thread, tight poll ----
    if (s == 0) {
      h_s[tid] = 0.f;
    } else {
      const u64* slot = slots + ((size_t)rep * NV + (s - 1)) * DD;
      u64 v = __hip_atomic_load(&slot[tid], __ATOMIC_RELAXED, __HIP_MEMORY_SCOPE_AGENT);
      while ((unsigned)v != (unsigned)s)
        v = __hip_atomic_load(&slot[tid], __ATOMIC_RELAXED, __HIP_MEMORY_SCOPE_AGENT);
      h_s[tid] = __uint_as_float((unsigned)(v >> 32));
    }
    __syncthreads();

    // ---- dot: 64 elems from registers, h from LDS (8-way broadcast) ----
    // column rotation (q+2l)&15 staggers banks: 2-way max (free per m136)
    float p = 0.f;
    const float4* h4 = (const float4*)h_s;
#pragma unroll
    for (int q = 0; q < 16; ++q) {
      const int qq = (q + 2 * l) & 15;
      float4 hv = h4[l * 16 + qq];
      p += wr[qq].x * hv.x + wr[qq].y * hv.y + wr[qq].z * hv.z + wr[qq].w * hv.w;
    }
    p += __shfl_down(p, 4, 8);
    p += __shfl_down(p, 2, 8);
    p += __shfl_down(p, 1, 8);
    if (l == 0) dot_s[r] = p;
    __syncthreads();

    // ---- activations (dims dl=tid<16) + 4-replica publish (wave 0) ----
    u64 pack = 0;
    if (tid < 16) {
      const float pi = gx_s[s][tid]      + dot_s[tid];
      const float pf = gx_s[s][16 + tid] + dot_s[16 + tid];
      const float pg = gx_s[s][32 + tid] + dot_s[32 + tid];
      const float po = gx_s[s][48 + tid] + dot_s[48 + tid];
      const float si = 1.f / (1.f + expf(-pi));
      const float sf = 1.f / (1.f + expf(-pf));
      const float so = 1.f / (1.f + expf(-po));
      c_reg = sf * c_reg + si * tanhf(pg);
      const float hn = so * tanhf(c_reg);
      pack = ((u64)__float_as_uint(hn) << 32) | (u64)(unsigned)(s + 1);
    }
    if (tid < 64) {
      u64 pk = __shfl(pack, tid & 15, 64);
      __hip_atomic_store(&slots[(((size_t)(tid >> 4)) * NV + s) * DD + wg * 16 + (tid & 15)],
                         pk, __ATOMIC_RELAXED, __HIP_MEMORY_SCOPE_AGENT);
    }
    // h_s rewritten only after this step's 2nd barrier -> next poll is safe
  }
}

// ---------------------------------------------------------------------------
// Kernel 4: classifier. 1 WG. Dispatch boundary = coherence; plain reads.
// ---------------------------------------------------------------------------
__global__ __launch_bounds__(256) void k_cls(const u64* __restrict__ slots,
                                             const float* __restrict__ w_cls,
                                             const float* __restrict__ b_cls,
                                             float* __restrict__ out) {
  const int tid = threadIdx.x;
  __shared__ __align__(16) float h_hist[NV][520];
  for (int f = tid; f < NV * DD; f += 256) {
    const int ss = f >> 9, d = f & 511;
    h_hist[ss][d] = __uint_as_float((unsigned)(slots[(size_t)ss * DD + d] >> 32));
  }
  __syncthreads();
  if (tid < NV * NCLS) {
    const int n = tid >> 3, cl = tid & 7;
    const float4* hv = (const float4*)&h_hist[n][0];
    const float4* wv = (const float4*)(w_cls + (size_t)cl * DD);
    float a = b_cls[cl];
#pragma unroll 8
    for (int q = 0; q < DD / 4; ++q) {
      float4 x = hv[q], y = wv[q];
      a += x.x * y.x + x.y * y.y + x.z * y.z + x.w * y.w;
    }
    out[tid] = a;
  }
}

extern "C" void kernel_launch(void* const* d_in, const int* in_sizes, int n_in,
                              void* d_out, int out_size, void* d_ws, size_t ws_size,
                              hipStream_t stream) {
  const float* base_out = (const float*)d_in[0];
  const float* dist     = (const float*)d_in[1];
  const float* w_a      = (const float*)d_in[2];
  const float* w_ih     = (const float*)d_in[3];
  const float* w_hh     = (const float*)d_in[4];
  const float* b_ih     = (const float*)d_in[5];
  const float* b_hh     = (const float*)d_in[6];
  const float* w_cls    = (const float*)d_in[7];
  const float* b_cls    = (const float*)d_in[8];
  float* out = (float*)d_out;

  float* ws = (float*)d_ws;
  float* part   = ws + PART_F;
  float* pooled = ws + POOLED_F;
  // Clean slot region if ws allows; else alias part (dead after k_pool;
  // tags 1..16 are denormal bit patterns a GEMM float can't hit).
  u64* slots = (ws_size >= SLOTC_END_BYTES) ? (u64*)(ws + SLOTC_F) : (u64*)ws;

  k_gemm<<<dim3(256), 256, 0, stream>>>(w_a, base_out, part);
  k_pool<<<dim3(256), 256, 0, stream>>>(part, dist, pooled);
  k_lstm<<<dim3(32), 512, 0, stream>>>(w_hh, w_ih, b_ih, b_hh, pooled, slots);
  k_cls<<<dim3(1), 256, 0, stream>>>(slots, w_cls, b_cls, out);
}